// Round 1
// baseline (1388.759 us; speedup 1.0000x reference)
//
#include <hip/hip_runtime.h>
#include <stdint.h>

#define B_SIZE  524288
#define NT      20        // 20 output tiles of 16 features: 16 gate tiles + 4 head tiles
#define GATE_T  16

typedef float f32x4  __attribute__((ext_vector_type(4)));
typedef short bf16x8 __attribute__((ext_vector_type(8)));

__device__ __forceinline__ uint16_t f2bf(float f) {
    uint32_t u = __float_as_uint(f);
    u += 0x7fffu + ((u >> 16) & 1u);   // round-to-nearest-even
    return (uint16_t)(u >> 16);
}

__device__ __forceinline__ float sigm(float v) {
    return __builtin_amdgcn_rcpf(1.0f + __expf(-v));
}
__device__ __forceinline__ float tanh_f(float v) {
    // tanh(x) = 1 - 2/(e^{2x}+1); exp overflow -> inf -> rcp=0 -> 1 (correct limit)
    return 1.0f - 2.0f * __builtin_amdgcn_rcpf(__expf(2.0f * v) + 1.0f);
}

// Pack weights into MFMA fragment order (used as A operand: A[m=lane&15][k=(lane>>4)*8+j]):
// chunk idx = t*256 + kb*64 + lane ; chunk holds 8 bf16 = W_all[t*16+(lane&15)][kb*32+(lane>>4)*8 + 0..7]
// W_all rows 0..255 = [W_ih | W_hh] (gate order i,f,g,o), rows 256..319 = W_o.
__global__ __launch_bounds__(256) void prep_weights(
    const float* __restrict__ W_ih, const float* __restrict__ W_hh,
    const float* __restrict__ b_ih, const float* __restrict__ b_hh,
    const float* __restrict__ W_o,  const float* __restrict__ b_o,
    uint16_t* __restrict__ wfrag, float* __restrict__ bias_all)
{
    int idx = blockIdx.x * 256 + threadIdx.x;
    if (idx < NT * 4 * 64) {
        int lane = idx & 63;
        int kb   = (idx >> 6) & 3;
        int t    = idx >> 8;
        int n    = t * 16 + (lane & 15);
        int k0   = kb * 32 + (lane >> 4) * 8;
        float v[8];
        if (n < 256) {
            if (k0 < 64) {
                #pragma unroll
                for (int j = 0; j < 8; ++j) v[j] = W_ih[n * 64 + k0 + j];
            } else {
                #pragma unroll
                for (int j = 0; j < 8; ++j) v[j] = W_hh[n * 64 + (k0 - 64) + j];
            }
        } else {
            #pragma unroll
            for (int j = 0; j < 8; ++j) v[j] = W_o[(n - 256) * 128 + k0 + j];
        }
        uint16_t* dst = wfrag + (size_t)idx * 8;
        #pragma unroll
        for (int j = 0; j < 8; ++j) dst[j] = f2bf(v[j]);
    }
    if (idx < NT * 16) {
        bias_all[idx] = (idx < 256) ? (b_ih[idx] + b_hh[idx]) : b_o[idx - 256];
    }
}

// LDS = exactly 80 KiB (weights only) -> two 1024-thread workgroups per CU
// (2 x 81920 B = 163840 B = full 160 KiB LDS), 32 waves/CU instead of 16.
// __launch_bounds__(1024, 8): 8 waves/EU -> pins VGPR alloc to <=64 (the tier edge).
__global__ __launch_bounds__(1024, 8) void lstm_fused(
    const float* __restrict__ x, const float* __restrict__ h0,
    const float* __restrict__ c0,
    const uint16_t* __restrict__ wfrag, const float* __restrict__ bias_all,
    float* __restrict__ out)
{
    __shared__ __align__(16) uint16_t lds_w[NT * 4 * 64 * 8]; // 81920 B: ALL weight tiles

    const int tid = threadIdx.x;
    {
        const uint4* src = (const uint4*)wfrag;
        uint4* dst = (uint4*)lds_w;
        #pragma unroll
        for (int i = 0; i < 5; ++i) dst[tid + i * 1024] = src[tid + i * 1024];
    }
    __syncthreads();

    const int wave = tid >> 6;
    const int lane = tid & 63;
    const int b    = lane & 15;   // C/D col = batch row within tile
    const int q    = lane >> 4;   // 0..3

    float* out_logp = out;
    float* out_h = out + (size_t)B_SIZE * 64;
    float* out_c = out + (size_t)2 * B_SIZE * 64;

    const int nwt = B_SIZE / 16;
    const int stride = gridDim.x * 16;

    for (int wt = blockIdx.x * 16 + wave; wt < nwt; wt += stride) {
        const int R = wt * 16;

        // ---- B fragments from x,h: lane holds combined[R+b][kb*32 + q*8 + j] ----
        bf16x8 bfr[4];
        {
            const float* xr = x  + (size_t)(R + b) * 64 + q * 8;
            const float* hr = h0 + (size_t)(R + b) * 64 + q * 8;
            f32x4 x0 = __builtin_nontemporal_load((const f32x4*)(xr));
            f32x4 x1 = __builtin_nontemporal_load((const f32x4*)(xr + 4));
            f32x4 x2 = __builtin_nontemporal_load((const f32x4*)(xr + 32));
            f32x4 x3 = __builtin_nontemporal_load((const f32x4*)(xr + 36));
            f32x4 ha = __builtin_nontemporal_load((const f32x4*)(hr));
            f32x4 hb = __builtin_nontemporal_load((const f32x4*)(hr + 4));
            f32x4 hc = __builtin_nontemporal_load((const f32x4*)(hr + 32));
            f32x4 hd = __builtin_nontemporal_load((const f32x4*)(hr + 36));
            #pragma unroll
            for (int j = 0; j < 4; ++j) {
                bfr[0][j]     = (short)f2bf(x0[j]);
                bfr[0][4 + j] = (short)f2bf(x1[j]);
                bfr[1][j]     = (short)f2bf(x2[j]);
                bfr[1][4 + j] = (short)f2bf(x3[j]);
                bfr[2][j]     = (short)f2bf(ha[j]);
                bfr[2][4 + j] = (short)f2bf(hb[j]);
                bfr[3][j]     = (short)f2bf(hc[j]);
                bfr[3][4 + j] = (short)f2bf(hd[j]);
            }
        }

        // opaque zero (SGPR) — prevents LICM from hoisting the 20 bias f32x4 loads
        // (hoisting would cost 80 live VGPRs -> occupancy tier drop)
        int zz; asm volatile("s_mov_b32 %0, 0" : "=s"(zz));

        // ---- acc seeded with bias from GLOBAL (1.25 KB, L1-resident):
        //      acc[t][r] = bias[t*16 + q*4 + r] ----
        f32x4 acc[NT];
        #pragma unroll
        for (int t = 0; t < NT; ++t)
            acc[t] = *(const f32x4*)(bias_all + t * 16 + q * 4 + zz);

        // ---- MFMA: weights as A (from LDS), x/h as B; 20 tiles x 4 kblocks ----
        #pragma unroll
        for (int kb = 0; kb < 4; ++kb) {
            #pragma unroll
            for (int t = 0; t < NT; ++t) {
                bf16x8 wf = *(const bf16x8*)(lds_w + ((t * 4 + kb) * 64 + lane) * 8);
                acc[t] = __builtin_amdgcn_mfma_f32_16x16x32_bf16(wf, bfr[kb], acc[t], 0, 0, 0);
            }
        }

        // ---- gate epilogue: lane holds features u*16+q*4+{0..3} of batch R+b ----
        // plain (cached) stores: let L2 merge the four 64B segments per 256B row
        // before eviction -> full-line HBM writes (nt stores gave 1.43x write amp)
        const float* cr = c0 + (size_t)(R + b) * 64;
        #pragma unroll
        for (int u = 0; u < 4; ++u) {
            f32x4 cv = __builtin_nontemporal_load((const f32x4*)(cr + u * 16 + q * 4));
            f32x4 cn, hn;
            #pragma unroll
            for (int r = 0; r < 4; ++r) {
                float ig = sigm(acc[u][r]);
                float fg = sigm(acc[4 + u][r]);
                float gg = tanh_f(acc[8 + u][r]);
                float og = sigm(acc[12 + u][r]);
                float c1 = fg * cv[r] + ig * gg;
                cn[r] = c1;
                hn[r] = og * tanh_f(c1);
            }
            size_t off = (size_t)(R + b) * 64 + u * 16 + q * 4;
            *(f32x4*)(out_c + off) = cn;
            *(f32x4*)(out_h + off) = hn;
        }

        // ---- head: logits in acc[16..19]; softmax over 64 = 16 in-lane + quads ----
        float m = acc[16][0];
        #pragma unroll
        for (int u = 0; u < 4; ++u)
            #pragma unroll
            for (int r = 0; r < 4; ++r) m = fmaxf(m, acc[16 + u][r]);
        m = fmaxf(m, __shfl_xor(m, 16));
        m = fmaxf(m, __shfl_xor(m, 32));
        float s = 0.0f;
        #pragma unroll
        for (int u = 0; u < 4; ++u)
            #pragma unroll
            for (int r = 0; r < 4; ++r) s += __expf(acc[16 + u][r] - m);
        s += __shfl_xor(s, 16);
        s += __shfl_xor(s, 32);
        float lse = m + __logf(s);
        #pragma unroll
        for (int u = 0; u < 4; ++u) {
            f32x4 lp;
            #pragma unroll
            for (int r = 0; r < 4; ++r) lp[r] = acc[16 + u][r] - lse;
            *(f32x4*)(out_logp + (size_t)(R + b) * 64 + u * 16 + q * 4) = lp;
        }
    }
}

extern "C" void kernel_launch(void* const* d_in, const int* in_sizes, int n_in,
                              void* d_out, int out_size, void* d_ws, size_t ws_size,
                              hipStream_t stream)
{
    const float* x    = (const float*)d_in[0];
    const float* h0   = (const float*)d_in[1];
    const float* c0   = (const float*)d_in[2];
    const float* W_ih = (const float*)d_in[3];
    const float* W_hh = (const float*)d_in[4];
    const float* b_ih = (const float*)d_in[5];
    const float* b_hh = (const float*)d_in[6];
    const float* W_o  = (const float*)d_in[7];
    const float* b_o  = (const float*)d_in[8];

    uint16_t* wfrag = (uint16_t*)d_ws;
    float* bias_all = (float*)((char*)d_ws + (size_t)NT * 4 * 64 * 8 * sizeof(uint16_t));

    prep_weights<<<20, 256, 0, stream>>>(W_ih, W_hh, b_ih, b_hh, W_o, b_o, wfrag, bias_all);
    lstm_fused<<<512, 1024, 0, stream>>>(x, h0, c0, wfrag, bias_all, (float*)d_out);
}

// Round 2
// 761.193 us; speedup vs baseline: 1.8244x; 1.8244x over previous
//
#include <hip/hip_runtime.h>
#include <stdint.h>

#define B_SIZE  524288
#define NT      20        // 20 output tiles of 16 features: 16 gate tiles + 4 head tiles
#define GATE_T  16

typedef float f32x4  __attribute__((ext_vector_type(4)));
typedef short bf16x8 __attribute__((ext_vector_type(8)));

__device__ __forceinline__ uint16_t f2bf(float f) {
    uint32_t u = __float_as_uint(f);
    u += 0x7fffu + ((u >> 16) & 1u);   // round-to-nearest-even
    return (uint16_t)(u >> 16);
}

__device__ __forceinline__ float sigm(float v) {
    return __builtin_amdgcn_rcpf(1.0f + __expf(-v));
}
__device__ __forceinline__ float tanh_f(float v) {
    // tanh(x) = 1 - 2/(e^{2x}+1); exp overflow -> inf -> rcp=0 -> 1 (correct limit)
    return 1.0f - 2.0f * __builtin_amdgcn_rcpf(__expf(2.0f * v) + 1.0f);
}

// Pack weights into MFMA fragment order (used as A operand: A[m=lane&15][k=(lane>>4)*8+j]):
// chunk idx = t*256 + kb*64 + lane ; chunk holds 8 bf16 = W_all[t*16+(lane&15)][kb*32+(lane>>4)*8 + 0..7]
// W_all rows 0..255 = [W_ih | W_hh] (gate order i,f,g,o), rows 256..319 = W_o.
__global__ __launch_bounds__(256) void prep_weights(
    const float* __restrict__ W_ih, const float* __restrict__ W_hh,
    const float* __restrict__ b_ih, const float* __restrict__ b_hh,
    const float* __restrict__ W_o,  const float* __restrict__ b_o,
    uint16_t* __restrict__ wfrag, float* __restrict__ bias_all)
{
    int idx = blockIdx.x * 256 + threadIdx.x;
    if (idx < NT * 4 * 64) {
        int lane = idx & 63;
        int kb   = (idx >> 6) & 3;
        int t    = idx >> 8;
        int n    = t * 16 + (lane & 15);
        int k0   = kb * 32 + (lane >> 4) * 8;
        float v[8];
        if (n < 256) {
            if (k0 < 64) {
                #pragma unroll
                for (int j = 0; j < 8; ++j) v[j] = W_ih[n * 64 + k0 + j];
            } else {
                #pragma unroll
                for (int j = 0; j < 8; ++j) v[j] = W_hh[n * 64 + (k0 - 64) + j];
            }
        } else {
            #pragma unroll
            for (int j = 0; j < 8; ++j) v[j] = W_o[(n - 256) * 128 + k0 + j];
        }
        uint16_t* dst = wfrag + (size_t)idx * 8;
        #pragma unroll
        for (int j = 0; j < 8; ++j) dst[j] = f2bf(v[j]);
    }
    if (idx < NT * 16) {
        bias_all[idx] = (idx < 256) ? (b_ih[idx] + b_hh[idx]) : b_o[idx - 256];
    }
}

// Dataflow restructured for the 64-reg/wave tier (2 blocks/CU):
//   - gate tiles processed in 4 groups of {i,f,g,o} x one 16-feature block:
//     only 4 f32x4 accumulators live at a time (16 floats, was 80)
//   - head tiles 16..19 processed last (softmax needs all 4 co-live)
// LDS = exactly 80 KiB (weights only) -> 2 x 1024-thread blocks/CU = 32 waves/CU.
// __launch_bounds__(1024, 8) now SATISFIABLE: peak live ~55-60 regs.
__global__ __launch_bounds__(1024, 8) void lstm_fused(
    const float* __restrict__ x, const float* __restrict__ h0,
    const float* __restrict__ c0,
    const uint16_t* __restrict__ wfrag, const float* __restrict__ bias_all,
    float* __restrict__ out)
{
    __shared__ __align__(16) uint16_t lds_w[NT * 4 * 64 * 8]; // 81920 B: ALL weight tiles

    const int tid = threadIdx.x;
    {
        const uint4* src = (const uint4*)wfrag;
        uint4* dst = (uint4*)lds_w;
        #pragma unroll
        for (int i = 0; i < 5; ++i) dst[tid + i * 1024] = src[tid + i * 1024];
    }
    __syncthreads();

    const int wave = tid >> 6;
    const int lane = tid & 63;
    const int b    = lane & 15;   // C/D col = batch row within tile
    const int q    = lane >> 4;   // 0..3

    float* out_logp = out;
    float* out_h = out + (size_t)B_SIZE * 64;
    float* out_c = out + (size_t)2 * B_SIZE * 64;

    const int nwt = B_SIZE / 16;
    const int stride = gridDim.x * 16;

    for (int wt = blockIdx.x * 16 + wave; wt < nwt; wt += stride) {
        const int R = wt * 16;

        // ---- B fragments from x,h: lane holds combined[R+b][kb*32 + q*8 + j] ----
        bf16x8 bfr[4];
        {
            const float* xr = x  + (size_t)(R + b) * 64 + q * 8;
            const float* hr = h0 + (size_t)(R + b) * 64 + q * 8;
            f32x4 x0 = __builtin_nontemporal_load((const f32x4*)(xr));
            f32x4 x1 = __builtin_nontemporal_load((const f32x4*)(xr + 4));
            f32x4 x2 = __builtin_nontemporal_load((const f32x4*)(xr + 32));
            f32x4 x3 = __builtin_nontemporal_load((const f32x4*)(xr + 36));
            f32x4 ha = __builtin_nontemporal_load((const f32x4*)(hr));
            f32x4 hb = __builtin_nontemporal_load((const f32x4*)(hr + 4));
            f32x4 hc = __builtin_nontemporal_load((const f32x4*)(hr + 32));
            f32x4 hd = __builtin_nontemporal_load((const f32x4*)(hr + 36));
            #pragma unroll
            for (int j = 0; j < 4; ++j) {
                bfr[0][j]     = (short)f2bf(x0[j]);
                bfr[0][4 + j] = (short)f2bf(x1[j]);
                bfr[1][j]     = (short)f2bf(x2[j]);
                bfr[1][4 + j] = (short)f2bf(x3[j]);
                bfr[2][j]     = (short)f2bf(ha[j]);
                bfr[2][4 + j] = (short)f2bf(hb[j]);
                bfr[3][j]     = (short)f2bf(hc[j]);
                bfr[3][4 + j] = (short)f2bf(hd[j]);
            }
        }

        // opaque zero (SGPR) — prevents LICM from hoisting the 20 bias f32x4 loads
        // (hoisting would cost 80 live VGPRs -> spill, see round-1 post-mortem)
        int zz; asm volatile("s_mov_b32 %0, 0" : "=s"(zz));

        const float* cr = c0 + (size_t)(R + b) * 64;

        // ---- gate groups: u = feature block; tiles {u, 4+u, 8+u, 12+u} = i,f,g,o.
        //      Only 4 accumulators live at a time. ----
        #pragma unroll
        for (int u = 0; u < 4; ++u) {
            f32x4 ai = *(const f32x4*)(bias_all + (u)      * 16 + q * 4 + zz);
            f32x4 af = *(const f32x4*)(bias_all + (4 + u)  * 16 + q * 4 + zz);
            f32x4 ag = *(const f32x4*)(bias_all + (8 + u)  * 16 + q * 4 + zz);
            f32x4 ao = *(const f32x4*)(bias_all + (12 + u) * 16 + q * 4 + zz);
            #pragma unroll
            for (int kb = 0; kb < 4; ++kb) {
                bf16x8 wi = *(const bf16x8*)(lds_w + (((u)      * 4 + kb) * 64 + lane) * 8);
                bf16x8 wf = *(const bf16x8*)(lds_w + (((4 + u)  * 4 + kb) * 64 + lane) * 8);
                bf16x8 wg = *(const bf16x8*)(lds_w + (((8 + u)  * 4 + kb) * 64 + lane) * 8);
                bf16x8 wo = *(const bf16x8*)(lds_w + (((12 + u) * 4 + kb) * 64 + lane) * 8);
                ai = __builtin_amdgcn_mfma_f32_16x16x32_bf16(wi, bfr[kb], ai, 0, 0, 0);
                af = __builtin_amdgcn_mfma_f32_16x16x32_bf16(wf, bfr[kb], af, 0, 0, 0);
                ag = __builtin_amdgcn_mfma_f32_16x16x32_bf16(wg, bfr[kb], ag, 0, 0, 0);
                ao = __builtin_amdgcn_mfma_f32_16x16x32_bf16(wo, bfr[kb], ao, 0, 0, 0);
            }
            // epilogue for this 16-feature block; cached stores -> L2 merges the
            // four 64B segments per 256B row into full-line HBM writes
            f32x4 cv = __builtin_nontemporal_load((const f32x4*)(cr + u * 16 + q * 4));
            f32x4 cn, hn;
            #pragma unroll
            for (int r = 0; r < 4; ++r) {
                float ig = sigm(ai[r]);
                float fg = sigm(af[r]);
                float gg = tanh_f(ag[r]);
                float og = sigm(ao[r]);
                float c1 = fg * cv[r] + ig * gg;
                cn[r] = c1;
                hn[r] = og * tanh_f(c1);
            }
            size_t off = (size_t)(R + b) * 64 + u * 16 + q * 4;
            *(f32x4*)(out_c + off) = cn;
            *(f32x4*)(out_h + off) = hn;
        }

        // ---- head: tiles 16..19 (all 4 co-live for the 64-wide softmax) ----
        f32x4 hacc[4];
        #pragma unroll
        for (int t2 = 0; t2 < 4; ++t2)
            hacc[t2] = *(const f32x4*)(bias_all + (16 + t2) * 16 + q * 4 + zz);
        #pragma unroll
        for (int kb = 0; kb < 4; ++kb) {
            #pragma unroll
            for (int t2 = 0; t2 < 4; ++t2) {
                bf16x8 wf = *(const bf16x8*)(lds_w + (((16 + t2) * 4 + kb) * 64 + lane) * 8);
                hacc[t2] = __builtin_amdgcn_mfma_f32_16x16x32_bf16(wf, bfr[kb], hacc[t2], 0, 0, 0);
            }
        }
        // softmax over 64 = 16 in-lane + quad shuffles
        float m = hacc[0][0];
        #pragma unroll
        for (int t2 = 0; t2 < 4; ++t2)
            #pragma unroll
            for (int r = 0; r < 4; ++r) m = fmaxf(m, hacc[t2][r]);
        m = fmaxf(m, __shfl_xor(m, 16));
        m = fmaxf(m, __shfl_xor(m, 32));
        float s = 0.0f;
        #pragma unroll
        for (int t2 = 0; t2 < 4; ++t2)
            #pragma unroll
            for (int r = 0; r < 4; ++r) s += __expf(hacc[t2][r] - m);
        s += __shfl_xor(s, 16);
        s += __shfl_xor(s, 32);
        float lse = m + __logf(s);
        #pragma unroll
        for (int t2 = 0; t2 < 4; ++t2) {
            f32x4 lp;
            #pragma unroll
            for (int r = 0; r < 4; ++r) lp[r] = hacc[t2][r] - lse;
            *(f32x4*)(out_logp + (size_t)(R + b) * 64 + t2 * 16 + q * 4) = lp;
        }
    }
}

extern "C" void kernel_launch(void* const* d_in, const int* in_sizes, int n_in,
                              void* d_out, int out_size, void* d_ws, size_t ws_size,
                              hipStream_t stream)
{
    const float* x    = (const float*)d_in[0];
    const float* h0   = (const float*)d_in[1];
    const float* c0   = (const float*)d_in[2];
    const float* W_ih = (const float*)d_in[3];
    const float* W_hh = (const float*)d_in[4];
    const float* b_ih = (const float*)d_in[5];
    const float* b_hh = (const float*)d_in[6];
    const float* W_o  = (const float*)d_in[7];
    const float* b_o  = (const float*)d_in[8];

    uint16_t* wfrag = (uint16_t*)d_ws;
    float* bias_all = (float*)((char*)d_ws + (size_t)NT * 4 * 64 * 8 * sizeof(uint16_t));

    prep_weights<<<20, 256, 0, stream>>>(W_ih, W_hh, b_ih, b_hh, W_o, b_o, wfrag, bias_all);
    lstm_fused<<<512, 1024, 0, stream>>>(x, h0, c0, wfrag, bias_all, (float*)d_out);
}

// Round 3
// 752.087 us; speedup vs baseline: 1.8465x; 1.0121x over previous
//
#include <hip/hip_runtime.h>
#include <stdint.h>

#define B_SIZE  524288
#define NT      20        // 20 output tiles of 16 features: 16 gate tiles + 4 head tiles
#define GATE_T  16

typedef float f32x4  __attribute__((ext_vector_type(4)));
typedef short bf16x8 __attribute__((ext_vector_type(8)));

__device__ __forceinline__ uint16_t f2bf(float f) {
    uint32_t u = __float_as_uint(f);
    u += 0x7fffu + ((u >> 16) & 1u);   // round-to-nearest-even
    return (uint16_t)(u >> 16);
}

__device__ __forceinline__ float sigm(float v) {
    return __builtin_amdgcn_rcpf(1.0f + __expf(-v));
}
__device__ __forceinline__ float tanh_f(float v) {
    // tanh(x) = 1 - 2/(e^{2x}+1); exp overflow -> inf -> rcp=0 -> 1 (correct limit)
    return 1.0f - 2.0f * __builtin_amdgcn_rcpf(__expf(2.0f * v) + 1.0f);
}

// Pack weights into MFMA fragment order (used as A operand: A[m=lane&15][k=(lane>>4)*8+j]):
// chunk idx = t*256 + kb*64 + lane ; chunk holds 8 bf16 = W_all[t*16+(lane&15)][kb*32+(lane>>4)*8 + 0..7]
// W_all rows 0..255 = [W_ih | W_hh] (gate order i,f,g,o), rows 256..319 = W_o.
__global__ __launch_bounds__(256) void prep_weights(
    const float* __restrict__ W_ih, const float* __restrict__ W_hh,
    const float* __restrict__ b_ih, const float* __restrict__ b_hh,
    const float* __restrict__ W_o,  const float* __restrict__ b_o,
    uint16_t* __restrict__ wfrag, float* __restrict__ bias_all)
{
    int idx = blockIdx.x * 256 + threadIdx.x;
    if (idx < NT * 4 * 64) {
        int lane = idx & 63;
        int kb   = (idx >> 6) & 3;
        int t    = idx >> 8;
        int n    = t * 16 + (lane & 15);
        int k0   = kb * 32 + (lane >> 4) * 8;
        float v[8];
        if (n < 256) {
            if (k0 < 64) {
                #pragma unroll
                for (int j = 0; j < 8; ++j) v[j] = W_ih[n * 64 + k0 + j];
            } else {
                #pragma unroll
                for (int j = 0; j < 8; ++j) v[j] = W_hh[n * 64 + (k0 - 64) + j];
            }
        } else {
            #pragma unroll
            for (int j = 0; j < 8; ++j) v[j] = W_o[(n - 256) * 128 + k0 + j];
        }
        uint16_t* dst = wfrag + (size_t)idx * 8;
        #pragma unroll
        for (int j = 0; j < 8; ++j) dst[j] = f2bf(v[j]);
    }
    if (idx < NT * 16) {
        bias_all[idx] = (idx < 256) ? (b_ih[idx] + b_hh[idx]) : b_o[idx - 256];
    }
}

// Gate tiles in 2 PAIRS of {i,f,g,o}x16-feature groups: epilogue of group u buffers
// cn/hn (+8 regs), group u+1 computes, then all 4 stores issue BACK-TO-BACK so each
// 128-B L2 line (= features of groups u,u+1) completes before eviction.
// Loads are plain cached (nt evict-first defeated x0/x1 line reuse).
// LDS = exactly 80 KiB -> 2 x 1024-thread blocks/CU = 32 waves/CU at the 64-reg tier.
__global__ __launch_bounds__(1024, 8) void lstm_fused(
    const float* __restrict__ x, const float* __restrict__ h0,
    const float* __restrict__ c0,
    const uint16_t* __restrict__ wfrag, const float* __restrict__ bias_all,
    float* __restrict__ out)
{
    __shared__ __align__(16) uint16_t lds_w[NT * 4 * 64 * 8]; // 81920 B: ALL weight tiles

    const int tid = threadIdx.x;
    {
        const uint4* src = (const uint4*)wfrag;
        uint4* dst = (uint4*)lds_w;
        #pragma unroll
        for (int i = 0; i < 5; ++i) dst[tid + i * 1024] = src[tid + i * 1024];
    }
    __syncthreads();

    const int wave = tid >> 6;
    const int lane = tid & 63;
    const int b    = lane & 15;   // C/D col = batch row within tile
    const int q    = lane >> 4;   // 0..3

    float* out_logp = out;
    float* out_h = out + (size_t)B_SIZE * 64;
    float* out_c = out + (size_t)2 * B_SIZE * 64;

    const int nwt = B_SIZE / 16;
    const int stride = gridDim.x * 16;

    for (int wt = blockIdx.x * 16 + wave; wt < nwt; wt += stride) {
        const int R = wt * 16;
        const size_t rowoff = (size_t)(R + b) * 64;

        // ---- B fragments from x,h: lane holds combined[R+b][kb*32 + q*8 + j] ----
        bf16x8 bfr[4];
        {
            const float* xr = x  + rowoff + q * 8;
            const float* hr = h0 + rowoff + q * 8;
            f32x4 x0 = *(const f32x4*)(xr);
            f32x4 x1 = *(const f32x4*)(xr + 4);
            f32x4 x2 = *(const f32x4*)(xr + 32);
            f32x4 x3 = *(const f32x4*)(xr + 36);
            f32x4 ha = *(const f32x4*)(hr);
            f32x4 hb = *(const f32x4*)(hr + 4);
            f32x4 hc = *(const f32x4*)(hr + 32);
            f32x4 hd = *(const f32x4*)(hr + 36);
            #pragma unroll
            for (int j = 0; j < 4; ++j) {
                bfr[0][j]     = (short)f2bf(x0[j]);
                bfr[0][4 + j] = (short)f2bf(x1[j]);
                bfr[1][j]     = (short)f2bf(x2[j]);
                bfr[1][4 + j] = (short)f2bf(x3[j]);
                bfr[2][j]     = (short)f2bf(ha[j]);
                bfr[2][4 + j] = (short)f2bf(hb[j]);
                bfr[3][j]     = (short)f2bf(hc[j]);
                bfr[3][4 + j] = (short)f2bf(hd[j]);
            }
        }

        // opaque zero (SGPR) — prevents LICM from hoisting the 24 bias f32x4 loads
        // (hoisting would cost 96 live VGPRs -> spill, see round-1 post-mortem)
        int zz; asm volatile("s_mov_b32 %0, 0" : "=s"(zz));

        const float* cr = c0 + rowoff;

        // ---- gate pairs: up=0 -> groups (0,1); up=1 -> groups (2,3) ----
        #pragma unroll
        for (int up = 0; up < 2; ++up) {
            const int u0 = up * 2;
            f32x4 cn0, hn0, cn1, hn1;

            // both c-vectors for the pair: adjacent loads -> one L2 line fetch
            f32x4 cv0 = *(const f32x4*)(cr + u0 * 16 + q * 4);
            f32x4 cv1 = *(const f32x4*)(cr + (u0 + 1) * 16 + q * 4);

            #pragma unroll
            for (int half = 0; half < 2; ++half) {
                const int u = u0 + half;
                f32x4 ai = *(const f32x4*)(bias_all + (u)      * 16 + q * 4 + zz);
                f32x4 af = *(const f32x4*)(bias_all + (4 + u)  * 16 + q * 4 + zz);
                f32x4 ag = *(const f32x4*)(bias_all + (8 + u)  * 16 + q * 4 + zz);
                f32x4 ao = *(const f32x4*)(bias_all + (12 + u) * 16 + q * 4 + zz);
                #pragma unroll
                for (int kb = 0; kb < 4; ++kb) {
                    bf16x8 wi = *(const bf16x8*)(lds_w + (((u)      * 4 + kb) * 64 + lane) * 8);
                    bf16x8 wf = *(const bf16x8*)(lds_w + (((4 + u)  * 4 + kb) * 64 + lane) * 8);
                    bf16x8 wg = *(const bf16x8*)(lds_w + (((8 + u)  * 4 + kb) * 64 + lane) * 8);
                    bf16x8 wo = *(const bf16x8*)(lds_w + (((12 + u) * 4 + kb) * 64 + lane) * 8);
                    ai = __builtin_amdgcn_mfma_f32_16x16x32_bf16(wi, bfr[kb], ai, 0, 0, 0);
                    af = __builtin_amdgcn_mfma_f32_16x16x32_bf16(wf, bfr[kb], af, 0, 0, 0);
                    ag = __builtin_amdgcn_mfma_f32_16x16x32_bf16(wg, bfr[kb], ag, 0, 0, 0);
                    ao = __builtin_amdgcn_mfma_f32_16x16x32_bf16(wo, bfr[kb], ao, 0, 0, 0);
                }
                f32x4 cv = half ? cv1 : cv0;
                f32x4 cn, hn;
                #pragma unroll
                for (int r = 0; r < 4; ++r) {
                    float ig = sigm(ai[r]);
                    float fg = sigm(af[r]);
                    float gg = tanh_f(ag[r]);
                    float og = sigm(ao[r]);
                    float c1 = fg * cv[r] + ig * gg;
                    cn[r] = c1;
                    hn[r] = og * tanh_f(c1);
                }
                if (half) { cn1 = cn; hn1 = hn; } else { cn0 = cn; hn0 = hn; }
            }

            // all 4 stores adjacent: both 64-B halves of each 128-B line written
            // within a few cycles -> full-line writeback, no RFO
            size_t off0 = rowoff + u0 * 16 + q * 4;
            size_t off1 = rowoff + (u0 + 1) * 16 + q * 4;
            *(f32x4*)(out_c + off0) = cn0;
            *(f32x4*)(out_c + off1) = cn1;
            *(f32x4*)(out_h + off0) = hn0;
            *(f32x4*)(out_h + off1) = hn1;
        }

        // ---- head: tiles 16..19 (all 4 co-live for the 64-wide softmax) ----
        f32x4 hacc[4];
        #pragma unroll
        for (int t2 = 0; t2 < 4; ++t2)
            hacc[t2] = *(const f32x4*)(bias_all + (16 + t2) * 16 + q * 4 + zz);
        #pragma unroll
        for (int kb = 0; kb < 4; ++kb) {
            #pragma unroll
            for (int t2 = 0; t2 < 4; ++t2) {
                bf16x8 wf = *(const bf16x8*)(lds_w + (((16 + t2) * 4 + kb) * 64 + lane) * 8);
                hacc[t2] = __builtin_amdgcn_mfma_f32_16x16x32_bf16(wf, bfr[kb], hacc[t2], 0, 0, 0);
            }
        }
        // softmax over 64 = 16 in-lane + quad shuffles
        float m = hacc[0][0];
        #pragma unroll
        for (int t2 = 0; t2 < 4; ++t2)
            #pragma unroll
            for (int r = 0; r < 4; ++r) m = fmaxf(m, hacc[t2][r]);
        m = fmaxf(m, __shfl_xor(m, 16));
        m = fmaxf(m, __shfl_xor(m, 32));
        float s = 0.0f;
        #pragma unroll
        for (int t2 = 0; t2 < 4; ++t2)
            #pragma unroll
            for (int r = 0; r < 4; ++r) s += __expf(hacc[t2][r] - m);
        s += __shfl_xor(s, 16);
        s += __shfl_xor(s, 32);
        float lse = m + __logf(s);
        // logp stores: all 4 back-to-back (lines complete immediately)
        #pragma unroll
        for (int t2 = 0; t2 < 4; ++t2) {
            f32x4 lp;
            #pragma unroll
            for (int r = 0; r < 4; ++r) lp[r] = hacc[t2][r] - lse;
            *(f32x4*)(out_logp + rowoff + t2 * 16 + q * 4) = lp;
        }
    }
}

extern "C" void kernel_launch(void* const* d_in, const int* in_sizes, int n_in,
                              void* d_out, int out_size, void* d_ws, size_t ws_size,
                              hipStream_t stream)
{
    const float* x    = (const float*)d_in[0];
    const float* h0   = (const float*)d_in[1];
    const float* c0   = (const float*)d_in[2];
    const float* W_ih = (const float*)d_in[3];
    const float* W_hh = (const float*)d_in[4];
    const float* b_ih = (const float*)d_in[5];
    const float* b_hh = (const float*)d_in[6];
    const float* W_o  = (const float*)d_in[7];
    const float* b_o  = (const float*)d_in[8];

    uint16_t* wfrag = (uint16_t*)d_ws;
    float* bias_all = (float*)((char*)d_ws + (size_t)NT * 4 * 64 * 8 * sizeof(uint16_t));

    prep_weights<<<20, 256, 0, stream>>>(W_ih, W_hh, b_ih, b_hh, W_o, b_o, wfrag, bias_all);
    lstm_fused<<<512, 1024, 0, stream>>>(x, h0, c0, wfrag, bias_all, (float*)d_out);
}